// Round 12
// baseline (165.671 us; speedup 1.0000x reference)
//
#include <hip/hip_runtime.h>
#include <math.h>

// ALCOVE cell: B=256, D=64, H=2048, O=32
// RHO=2, TAU=1, BETA=6.5, GAMMA=0, PHI=2, LAM_A=0.001, LAM_W=0.003
//
// R15: o-split for TLP. gx is ELEMENTWISE in o, so block (b, half) owns
//   output columns half*16..+15 end-to-end with NO cross-block deps:
//   - phase 1: full s/r for all 2048 h (redundant x2 per b; ~2us VALU)
//   - phase 2: x_out for its 16 o's (reads only its 32MB assoc half)
//   - gx for its 16 o's (elementwise) + out0 half
//   - phase 3 (merged): one assoc pass -> coeff partial (g_s over its
//     16 o's; halves sum linearly) + assoc-update stores
//   - LDS-only barrier (lgkmcnt, NOT vmcnt) -> 66MB store drain hides
//     under phase 4 (R9's proven trick, one phase earlier)
//   - phase 4: partial g_att -> gatt_part[b][half][d]; k3 adds halves.
//   Grid 512 = 2 blocks/CU co-resident (LDS 19KB, VGPR ~60): when one
//   block stalls on assoc loads/barriers, the sibling's compute runs.
//   half = bid>>8 so both halves of b share a CU (L1-shared ct/coords,
//   same-128B-line assoc writes merge in L1/L2).
//   R8-R14 lesson: compiler refuses 64-reg residency (VGPR pinned 60 at
//   every budget) -> stop fighting regalloc, buy latency hiding with TLP.
//
// ws: ct [D*H] (512 KB) + gatt_part [B*2*D] (128 KB).

#define BB 256
#define DD 64
#define HH 2048
#define OO 32
#define BETA 6.5f
#define PHI 2.0f
#define LAM_A 0.001f
#define LAM_W 0.003f
#define NT0 256
#define NT 512
#define NW (NT / 64)            // 8 waves
#define NCH (HH / (NT / 4))     // 16 chunks (128 h-rows each)

__global__ __launch_bounds__(NT0) void k0_transpose(
    const float* __restrict__ coords, float* __restrict__ ct)
{
    int idx = blockIdx.x * NT0 + threadIdx.x;   // 0 .. D*H-1, ct-linear
    int d = idx >> 11;                          // / HH
    int h = idx & (HH - 1);
    ct[idx] = coords[h * DD + d];
}

__global__ __launch_bounds__(NT, 4) void k_cell(
    const float* __restrict__ z,
    const float* __restrict__ one_hot,
    const float* __restrict__ att,
    const float* __restrict__ assoc,
    const float* __restrict__ coords,
    const float* __restrict__ ct,
    float* __restrict__ gatt_part,
    float* __restrict__ out)
{
    __shared__ float2 za[DD];           // (z_d, att_d)
    __shared__ float  s_loc[HH];        // 8 KB: similarity s
    __shared__ float  rc_loc[HH];       // 8 KB: r, then coeff-partial
    __shared__ float  wredf[NW * 16];   // per-wave x_out partials (16 o)
    __shared__ float  redf[NT];         // g_att reduction
    __shared__ float  gx_s[16];         // this half's gx

    const int b    = blockIdx.x & (BB - 1);
    const int half = blockIdx.x >> 8;          // 0/1: o-columns half*16..+15
    const int t    = threadIdx.x;
    const int o4   = t & 3;              // float4 column within the half
    const int hl   = t >> 2;             // 0..127

    if (t < DD)
        za[t] = make_float2(z[b * DD + t], att[b * DD + t]);
    __syncthreads();

    // ---- phase 1: s/r for ALL h (redundant across the 2 halves; cheap,
    //      and the sibling block's memory phases hide under it) ----
    #pragma unroll
    for (int i = 0; i < HH / NT; ++i) {          // 4 rounds of 512 h
        const int h = i * NT + t;
        float S = 0.0f;
        const float* ctp = ct + h;
        #pragma unroll 16
        for (int d = 0; d < DD; ++d) {
            float2 p = za[d];                    // broadcast ds_read_b64
            float c = ctp[d * HH];               // coalesced, L2/L1-hit
            float diff = p.x - c;
            S = fmaf(p.y * diff, diff, S);
        }
        S = S < 0.0f ? 0.0f : S;
        float dd = sqrtf(S);
        float sh = expf(-BETA * dd);
        s_loc[h]  = sh;
        rc_loc[h] = (dd > 0.0f) ? (-BETA * sh / (2.0f * dd)) : 0.0f;
    }
    __syncthreads();

    // ---- phase 2: x_out for this half's 16 o's (32MB assoc half) ----
    const float4* assoc4 = (const float4*)(assoc + (size_t)b * HH * OO);
    const int ocol = half * 4 + o4;              // float4 column in [0,8)

    float4 acc = make_float4(0.f, 0.f, 0.f, 0.f);
    #pragma unroll
    for (int ch = 0; ch < NCH; ++ch) {
        int hloc = ch * (NT / 4) + hl;
        float s2 = s_loc[hloc];                  // 4-way broadcast
        float4 a = assoc4[hloc * (OO / 4) + ocol];
        acc.x = fmaf(s2, a.x, acc.x);
        acc.y = fmaf(s2, a.y, acc.y);
        acc.z = fmaf(s2, a.z, acc.z);
        acc.w = fmaf(s2, a.w, acc.w);
    }
    // reduce over hl-rows inside each wave (lane bits 2..5)
    #pragma unroll
    for (int m = 4; m <= 32; m <<= 1) {
        acc.x += __shfl_xor(acc.x, m, 64);
        acc.y += __shfl_xor(acc.y, m, 64);
        acc.z += __shfl_xor(acc.z, m, 64);
        acc.w += __shfl_xor(acc.w, m, 64);
    }
    if ((t & 63) < 4) {                          // lane o4 of each wave
        int w = t >> 6;
        wredf[w * 16 + o4 * 4 + 0] = acc.x;
        wredf[w * 16 + o4 * 4 + 1] = acc.y;
        wredf[w * 16 + o4 * 4 + 2] = acc.z;
        wredf[w * 16 + o4 * 4 + 3] = acc.w;
    }
    __syncthreads();

    // ---- gx for this half (elementwise in o) + output 0 half ----
    if (t < 16) {
        float x = 0.0f;
        #pragma unroll
        for (int w = 0; w < NW; ++w)
            x += wredf[w * 16 + t];
        float oh = one_hot[b * OO + half * 16 + t];
        float tmin = fminf(-1.0f, x);
        float tmax = fmaxf(1.0f, x);
        float teacher = tmin - oh * tmin + oh * tmax;
        gx_s[t] = (2.0f / OO) * (x - teacher);   // note: /OO (full O mean)
        out[b * OO + half * 16 + t] = PHI * x;   // output 0 (our 16 o's)
    }
    __syncthreads();

    // ---- phase 3 (merged): coeff-partial + assoc update, ONE pass ----
    const float4 gxv = ((const float4*)gx_s)[o4];
    float4* out_assoc4 = (float4*)(out + BB * OO + BB * DD)
                       + (size_t)b * HH * (OO / 4);
    #pragma unroll
    for (int ch = 0; ch < NCH; ++ch) {
        int hloc = ch * (NT / 4) + hl;
        float4 a = assoc4[hloc * (OO / 4) + ocol];   // L2/L3-warm re-read
        // partial g_s over this half's 16 o's
        float part = a.x * gxv.x + a.y * gxv.y + a.z * gxv.z + a.w * gxv.w;
        part += __shfl_xor(part, 1, 64);
        part += __shfl_xor(part, 2, 64);
        if (o4 == 0)
            rc_loc[hloc] *= part;                // coeff partial = r * g_s_half
        // assoc update for our columns (fire-and-forget store)
        float w = LAM_W * s_loc[hloc];
        float4 na;
        na.x = fmaf(-w, gxv.x, a.x);
        na.y = fmaf(-w, gxv.y, a.y);
        na.z = fmaf(-w, gxv.z, a.z);
        na.w = fmaf(-w, gxv.w, a.w);
        out_assoc4[hloc * (OO / 4) + ocol] = na; // output 2 (our columns)
    }
    // LDS-only barrier: rc_loc (ds_write) visibility WITHOUT draining the
    // 32MB/block global store stream -> stores drain under phase 4.
    asm volatile("s_waitcnt lgkmcnt(0)\n\ts_barrier" ::: "memory");

    // ---- phase 4: partial g_att (this half's coeff) ----
    {
        const int lane = t & 63, wv = t >> 6;
        const float zd = za[lane].x;
        float ga = 0.0f;
        #pragma unroll 8
        for (int i = 0; i < HH / NW; ++i) {      // 256 h per wave
            int hloc = wv * (HH / NW) + i;
            float cf = rc_loc[hloc];             // same-address broadcast
            float c = coords[(size_t)hloc * DD + lane];  // coalesced, L2-hit
            float diff = zd - c;
            ga = fmaf(cf * diff, diff, ga);
        }
        redf[t] = ga;
    }
    asm volatile("s_waitcnt lgkmcnt(0)\n\ts_barrier" ::: "memory");
    if (t < DD) {
        float g = 0.0f;
        #pragma unroll
        for (int w = 0; w < NW; ++w)
            g += redf[w * 64 + t];               // conflict-free rows
        gatt_part[((size_t)b * 2 + half) * DD + t] = g;
    }
    // kernel end drains the assoc stores
}

__global__ __launch_bounds__(NT0) void k3_att(
    const float* __restrict__ att,
    const float* __restrict__ gatt_part,
    float* __restrict__ out)
{
    int idx = blockIdx.x * NT0 + threadIdx.x;    // 0 .. B*D-1
    int b = idx >> 6;
    int d = idx & 63;
    float g = gatt_part[((size_t)b * 2 + 0) * DD + d]
            + gatt_part[((size_t)b * 2 + 1) * DD + d];
    float na = att[b * DD + d] - LAM_A * g;
    out[BB * OO + idx] = na > 0.0f ? na : 0.0f;  // output 1
}

extern "C" void kernel_launch(void* const* d_in, const int* in_sizes, int n_in,
                              void* d_out, int out_size, void* d_ws, size_t ws_size,
                              hipStream_t stream) {
    const float* z       = (const float*)d_in[0];
    const float* one_hot = (const float*)d_in[1];
    const float* att     = (const float*)d_in[2];
    const float* assoc   = (const float*)d_in[3];
    const float* coords  = (const float*)d_in[4];
    float* out = (float*)d_out;

    float* ws = (float*)d_ws;
    float* ct        = ws;                       // D*H floats
    float* gatt_part = ct + DD * HH;             // B*2*D floats

    k0_transpose<<<dim3((DD * HH) / NT0), dim3(NT0), 0, stream>>>(coords, ct);
    k_cell<<<dim3(BB * 2), dim3(NT), 0, stream>>>(z, one_hot, att, assoc,
                                                  coords, ct, gatt_part, out);
    k3_att<<<dim3((BB * DD) / NT0), dim3(NT0), 0, stream>>>(att, gatt_part, out);
}